// Round 1
// 594.056 us; speedup vs baseline: 1.1360x; 1.1360x over previous
//
#include <hip/hip_runtime.h>

#define HDIM 768

constexpr int KC    = 32;          // k-columns per K-half staged per chunk
constexpr int KHALF = HDIM / 2;    // 384
constexpr int NCH   = KHALF / KC;  // 12 chunks
constexpr int RPB   = 128;         // rows per block
constexpr int PITCH = 2 * KC + 4;  // 68 floats: 272B pitch, 16B-aligned, conflict-free (verified R1)

// One W float4 load feeds BOTH rows of the thread's register tile (8 FMAs/load).
__device__ __forceinline__ void dot4x2(float& a0, float& a1,
                                       const float4 x0, const float4 x1,
                                       const float* __restrict__ Wrow, int kb) {
    // kb carries an opaque VGPR zero -> compiler must keep this a VECTOR load
    // (global_load_dwordx4, in-order vmcnt) instead of scalarizing to s_load
    // batches that blow the SGPR budget and force lgkmcnt(0) drains.
    const float4 w = *(const float4*)(Wrow + kb);
    a0 = fmaf(x0.x, w.x, a0); a1 = fmaf(x1.x, w.x, a1);
    a0 = fmaf(x0.y, w.y, a0); a1 = fmaf(x1.y, w.y, a1);
    a0 = fmaf(x0.z, w.z, a0); a1 = fmaf(x1.z, w.z, a1);
    a0 = fmaf(x0.w, w.w, a0); a1 = fmaf(x1.w, w.w, a1);
}

// Epilogue for one row given its 17 fp32-exact head accumulators.
#define WRITE_ROW(ACC, ROW)                                                   \
    do {                                                                      \
        const int row_ = (ROW);                                               \
        if (row_ < B) {                                                       \
            const float oa0 = ACC[0] + ba[0];                                 \
            const float oa1 = ACC[1] + ba[1];                                 \
            const bool active = oa1 > oa0;                                    \
            const float tb0 = ACC[2] + bb[0];                                 \
            const float tb1 = ACC[3] + bb[1];                                 \
            const float tb2 = ACC[4] + bb[2];                                 \
            const float tb3 = ACC[5] + bb[3];                                 \
            int   p = 0;                                                      \
            float m = tb0;                                                    \
            if (tb1 > m) { m = tb1; p = 1; }                                  \
            if (tb2 > m) { m = tb2; p = 2; }                                  \
            if (tb3 > m) { m = tb3; p = 3; }                                  \
            float* oa = out + (size_t)2 * row_;                               \
            oa[0] = oa0;                                                      \
            oa[1] = oa1;                                                      \
            float* ob = out + (size_t)2 * B + (size_t)5 * row_;               \
            ob[0] = 0.f;                                                      \
            ob[1] = active ? tb0 : 0.f;                                       \
            ob[2] = active ? tb1 : 0.f;                                       \
            ob[3] = active ? tb2 : 0.f;                                       \
            ob[4] = active ? tb3 : 0.f;                                       \
            const bool m0 = active && (p == 0);                               \
            const bool m1 = active && (p == 1);                               \
            const bool m2 = active && (p == 2);                               \
            const bool m3 = active && (p == 3);                               \
            float* oc = out + (size_t)7 * B + (size_t)11 * row_;              \
            oc[0]  = m0 ? ACC[6]  + bc1[0] : 0.f;                             \
            oc[1]  = m0 ? ACC[7]  + bc1[1] : 0.f;                             \
            oc[2]  = m1 ? ACC[8]  + bc2[0] : 0.f;                             \
            oc[3]  = m1 ? ACC[9]  + bc2[1] : 0.f;                             \
            oc[4]  = m1 ? ACC[10] + bc2[2] : 0.f;                             \
            oc[5]  = m2 ? ACC[11] + bc3[0] : 0.f;                             \
            oc[6]  = m2 ? ACC[12] + bc3[1] : 0.f;                             \
            oc[7]  = m2 ? ACC[13] + bc3[2] : 0.f;                             \
            oc[8]  = m2 ? ACC[14] + bc3[3] : 0.f;                             \
            oc[9]  = m3 ? ACC[15] + bc4[0] : 0.f;                             \
            oc[10] = m3 ? ACC[16] + bc4[1] : 0.f;                             \
        }                                                                     \
    } while (0)

__global__ __launch_bounds__(128, 2)
void hier_fused(const float* __restrict__ x,
                const float* __restrict__ Wa,  const float* __restrict__ ba,
                const float* __restrict__ Wb,  const float* __restrict__ bb,
                const float* __restrict__ Wc1, const float* __restrict__ bc1,
                const float* __restrict__ Wc2, const float* __restrict__ bc2,
                const float* __restrict__ Wc3, const float* __restrict__ bc3,
                const float* __restrict__ Wc4, const float* __restrict__ bc4,
                float* __restrict__ out, int B)
{
    __shared__ float xs[RPB * PITCH];   // 128*68*4 = 34816 B -> 4 blocks/CU

    const int t       = threadIdx.x;    // 0..127
    const int rr      = t & 63;         // first row of this thread's 2-row tile
    const int kh      = t >> 6;         // K-half: 0 -> k[0,384), 1 -> k[384,768)
    const int rowBase = blockIdx.x * RPB;

    int vz;
    asm("v_mov_b32 %0, 0" : "=v"(vz));  // opaque zero: defeats scalar-load promotion

    float ac0[17], ac1[17];             // rows rr and rr+64
#pragma unroll
    for (int j = 0; j < 17; ++j) { ac0[j] = 0.f; ac1[j] = 0.f; }

    // staging map: 16 consecutive lanes cover one row's 64 staged floats
    const int col4 = (t & 15) * 4;                      // 0..60
    const int grp  = t >> 4;                            // 0..7
    const int gOff = (col4 < KC) ? col4                 // half-0 slice
                                 : (KHALF - KC + col4); // half-1 slice

    for (int c = 0; c < NCH; ++c) {
        __syncthreads();                 // previous chunk's compute done
        const int gcol = c * KC + gOff;
#pragma unroll
        for (int i = 0; i < 16; ++i) {
            int r2  = grp + i * 8;                      // 0..127
            int row = rowBase + r2;
            if (row >= B) row = B - 1;
            const float4 v = *(const float4*)&x[(size_t)row * HDIM + gcol];
            *(float4*)&xs[r2 * PITCH + col4] = v;
        }
        __syncthreads();

        const float* xr0   = &xs[rr * PITCH + kh * KC];
        const float* xr1   = xr0 + 64 * PITCH;
        const int    kbase = kh * KHALF + c * KC + vz;
#pragma unroll 2
        for (int kk = 0; kk < KC; kk += 4) {
            const float4 xv0 = *(const float4*)(xr0 + kk);
            const float4 xv1 = *(const float4*)(xr1 + kk);
            const int kb = kbase + kk;
            dot4x2(ac0[0],  ac1[0],  xv0, xv1, Wa,              kb);
            dot4x2(ac0[1],  ac1[1],  xv0, xv1, Wa  +     HDIM,  kb);
            dot4x2(ac0[2],  ac1[2],  xv0, xv1, Wb,              kb);
            dot4x2(ac0[3],  ac1[3],  xv0, xv1, Wb  +     HDIM,  kb);
            dot4x2(ac0[4],  ac1[4],  xv0, xv1, Wb  + 2 * HDIM,  kb);
            dot4x2(ac0[5],  ac1[5],  xv0, xv1, Wb  + 3 * HDIM,  kb);
            dot4x2(ac0[6],  ac1[6],  xv0, xv1, Wc1,             kb);
            dot4x2(ac0[7],  ac1[7],  xv0, xv1, Wc1 +     HDIM,  kb);
            dot4x2(ac0[8],  ac1[8],  xv0, xv1, Wc2,             kb);
            dot4x2(ac0[9],  ac1[9],  xv0, xv1, Wc2 +     HDIM,  kb);
            dot4x2(ac0[10], ac1[10], xv0, xv1, Wc2 + 2 * HDIM,  kb);
            dot4x2(ac0[11], ac1[11], xv0, xv1, Wc3,             kb);
            dot4x2(ac0[12], ac1[12], xv0, xv1, Wc3 +     HDIM,  kb);
            dot4x2(ac0[13], ac1[13], xv0, xv1, Wc3 + 2 * HDIM,  kb);
            dot4x2(ac0[14], ac1[14], xv0, xv1, Wc3 + 3 * HDIM,  kb);
            dot4x2(ac0[15], ac1[15], xv0, xv1, Wc4,             kb);
            dot4x2(ac0[16], ac1[16], xv0, xv1, Wc4 +     HDIM,  kb);
        }
    }

    // combine the two K-half partials through LDS (xs is dead now)
    __syncthreads();
    if (kh == 1) {
#pragma unroll
        for (int j = 0; j < 17; ++j) {
            xs[rr * 19 + j]        = ac0[j];
            xs[(rr + 64) * 19 + j] = ac1[j];
        }
    }
    __syncthreads();
    if (kh != 0) return;

#pragma unroll
    for (int j = 0; j < 17; ++j) {
        ac0[j] += xs[rr * 19 + j];
        ac1[j] += xs[(rr + 64) * 19 + j];
    }

    WRITE_ROW(ac0, rowBase + rr);
    WRITE_ROW(ac1, rowBase + rr + 64);
}

extern "C" void kernel_launch(void* const* d_in, const int* in_sizes, int n_in,
                              void* d_out, int out_size, void* d_ws, size_t ws_size,
                              hipStream_t stream) {
    const float* x   = (const float*)d_in[0];
    const float* Wa  = (const float*)d_in[1];
    const float* ba  = (const float*)d_in[2];
    const float* Wb  = (const float*)d_in[3];
    const float* bb  = (const float*)d_in[4];
    const float* Wc1 = (const float*)d_in[5];
    const float* bc1 = (const float*)d_in[6];
    const float* Wc2 = (const float*)d_in[7];
    const float* bc2 = (const float*)d_in[8];
    const float* Wc3 = (const float*)d_in[9];
    const float* bc3 = (const float*)d_in[10];
    const float* Wc4 = (const float*)d_in[11];
    const float* bc4 = (const float*)d_in[12];

    const int B  = in_sizes[0] / HDIM;
    const int nb = (B + RPB - 1) / RPB;

    hipLaunchKernelGGL(hier_fused, dim3(nb), dim3(128), 0, stream,
                       x, Wa, ba, Wb, bb, Wc1, bc1, Wc2, bc2, Wc3, bc3, Wc4, bc4,
                       (float*)d_out, B);
}

// Round 2
// 591.211 us; speedup vs baseline: 1.1414x; 1.0048x over previous
//
#include <hip/hip_runtime.h>

#define HDIM 768

constexpr int KC    = 32;          // k-columns per K-half staged per chunk
constexpr int KHALF = HDIM / 2;    // 384
constexpr int NCH   = KHALF / KC;  // 12 chunks
constexpr int RPB   = 128;         // rows per block
constexpr int PITCH = 2 * KC + 4;  // 68 floats: 272B pitch, 16B-aligned, conflict-free (verified R1)

// head j -> (weight array, row within it). Expansion order is FIXED and must
// stay identical between LOADW and FMAW so accumulation order (and absmax)
// matches previous rounds exactly.
#define W_LIST(OP)                                                            \
    OP(0,  Wa,  0) OP(1,  Wa,  1)                                             \
    OP(2,  Wb,  0) OP(3,  Wb,  1) OP(4,  Wb,  2) OP(5,  Wb,  3)               \
    OP(6,  Wc1, 0) OP(7,  Wc1, 1)                                             \
    OP(8,  Wc2, 0) OP(9,  Wc2, 1) OP(10, Wc2, 2)                              \
    OP(11, Wc3, 0) OP(12, Wc3, 1) OP(13, Wc3, 2) OP(14, Wc3, 3)               \
    OP(15, Wc4, 0) OP(16, Wc4, 1)

// Batched W load: all 17 float4 loads issued back-to-back so the compiler
// emits one global_load_dwordx4 cluster (one latency exposure per batch,
// not per load). kb carries an opaque VGPR zero -> stays a VECTOR load.
#define LOADW(j, WP, R) const float4 w##j = *(const float4*)((WP) + (R) * HDIM + kb);

// FMA batch: per-accumulator op order identical to the previous dot4x2
// sequence (head-major, then x,y,z,w) -> bit-identical accumulation.
#define FMAW(j, WP, R)                                                        \
    ac0[j] = fmaf(xv0.x, w##j.x, ac0[j]); ac1[j] = fmaf(xv1.x, w##j.x, ac1[j]); \
    ac0[j] = fmaf(xv0.y, w##j.y, ac0[j]); ac1[j] = fmaf(xv1.y, w##j.y, ac1[j]); \
    ac0[j] = fmaf(xv0.z, w##j.z, ac0[j]); ac1[j] = fmaf(xv1.z, w##j.z, ac1[j]); \
    ac0[j] = fmaf(xv0.w, w##j.w, ac0[j]); ac1[j] = fmaf(xv1.w, w##j.w, ac1[j]);

// Epilogue for one row given its 17 fp32-exact head accumulators.
#define WRITE_ROW(ACC, ROW)                                                   \
    do {                                                                      \
        const int row_ = (ROW);                                               \
        if (row_ < B) {                                                       \
            const float oa0 = ACC[0] + ba[0];                                 \
            const float oa1 = ACC[1] + ba[1];                                 \
            const bool active = oa1 > oa0;                                    \
            const float tb0 = ACC[2] + bb[0];                                 \
            const float tb1 = ACC[3] + bb[1];                                 \
            const float tb2 = ACC[4] + bb[2];                                 \
            const float tb3 = ACC[5] + bb[3];                                 \
            int   p = 0;                                                      \
            float m = tb0;                                                    \
            if (tb1 > m) { m = tb1; p = 1; }                                  \
            if (tb2 > m) { m = tb2; p = 2; }                                  \
            if (tb3 > m) { m = tb3; p = 3; }                                  \
            float* oa = out + (size_t)2 * row_;                               \
            oa[0] = oa0;                                                      \
            oa[1] = oa1;                                                      \
            float* ob = out + (size_t)2 * B + (size_t)5 * row_;               \
            ob[0] = 0.f;                                                      \
            ob[1] = active ? tb0 : 0.f;                                       \
            ob[2] = active ? tb1 : 0.f;                                       \
            ob[3] = active ? tb2 : 0.f;                                       \
            ob[4] = active ? tb3 : 0.f;                                       \
            const bool m0 = active && (p == 0);                               \
            const bool m1 = active && (p == 1);                               \
            const bool m2 = active && (p == 2);                               \
            const bool m3 = active && (p == 3);                               \
            float* oc = out + (size_t)7 * B + (size_t)11 * row_;              \
            oc[0]  = m0 ? ACC[6]  + bc1[0] : 0.f;                             \
            oc[1]  = m0 ? ACC[7]  + bc1[1] : 0.f;                             \
            oc[2]  = m1 ? ACC[8]  + bc2[0] : 0.f;                             \
            oc[3]  = m1 ? ACC[9]  + bc2[1] : 0.f;                             \
            oc[4]  = m1 ? ACC[10] + bc2[2] : 0.f;                             \
            oc[5]  = m2 ? ACC[11] + bc3[0] : 0.f;                             \
            oc[6]  = m2 ? ACC[12] + bc3[1] : 0.f;                             \
            oc[7]  = m2 ? ACC[13] + bc3[2] : 0.f;                             \
            oc[8]  = m2 ? ACC[14] + bc3[3] : 0.f;                             \
            oc[9]  = m3 ? ACC[15] + bc4[0] : 0.f;                             \
            oc[10] = m3 ? ACC[16] + bc4[1] : 0.f;                             \
        }                                                                     \
    } while (0)

__global__ __launch_bounds__(128, 2)
void hier_fused(const float* __restrict__ x,
                const float* __restrict__ Wa,  const float* __restrict__ ba,
                const float* __restrict__ Wb,  const float* __restrict__ bb,
                const float* __restrict__ Wc1, const float* __restrict__ bc1,
                const float* __restrict__ Wc2, const float* __restrict__ bc2,
                const float* __restrict__ Wc3, const float* __restrict__ bc3,
                const float* __restrict__ Wc4, const float* __restrict__ bc4,
                float* __restrict__ out, int B)
{
    __shared__ float xs[RPB * PITCH];   // 128*68*4 = 34816 B -> 4 blocks/CU

    const int t       = threadIdx.x;    // 0..127
    const int rr      = t & 63;         // first row of this thread's 2-row tile
    const int kh      = t >> 6;         // K-half: 0 -> k[0,384), 1 -> k[384,768)
    const int rowBase = blockIdx.x * RPB;

    int vz;
    asm("v_mov_b32 %0, 0" : "=v"(vz));  // opaque zero: defeats scalar-load promotion

    float ac0[17], ac1[17];             // rows rr and rr+64
#pragma unroll
    for (int j = 0; j < 17; ++j) { ac0[j] = 0.f; ac1[j] = 0.f; }

    // staging map: 16 consecutive lanes cover one row's 64 staged floats
    const int col4 = (t & 15) * 4;                      // 0..60
    const int grp  = t >> 4;                            // 0..7
    const int gOff = (col4 < KC) ? col4                 // half-0 slice
                                 : (KHALF - KC + col4); // half-1 slice

    for (int c = 0; c < NCH; ++c) {
        __syncthreads();                 // previous chunk's compute done
        const int gcol = c * KC + gOff;
#pragma unroll
        for (int i = 0; i < 16; ++i) {
            int r2  = grp + i * 8;                      // 0..127
            int row = rowBase + r2;
            if (row >= B) row = B - 1;
            const float4 v = *(const float4*)&x[(size_t)row * HDIM + gcol];
            *(float4*)&xs[r2 * PITCH + col4] = v;
        }
        __syncthreads();

        const float* xr0   = &xs[rr * PITCH + kh * KC];
        const float* xr1   = xr0 + 64 * PITCH;
        const int    kbase = kh * KHALF + c * KC + vz;
#pragma unroll 2
        for (int kk = 0; kk < KC; kk += 4) {
            const float4 xv0 = *(const float4*)(xr0 + kk);
            const float4 xv1 = *(const float4*)(xr1 + kk);
            const int kb = kbase + kk;
            W_LIST(LOADW)   // 17 global_load_dwordx4 issued as one cluster
            W_LIST(FMAW)    // 136 FMAs, same accumulation order as before
        }
    }

    // combine the two K-half partials through LDS (xs is dead now)
    __syncthreads();
    if (kh == 1) {
#pragma unroll
        for (int j = 0; j < 17; ++j) {
            xs[rr * 19 + j]        = ac0[j];
            xs[(rr + 64) * 19 + j] = ac1[j];
        }
    }
    __syncthreads();
    if (kh != 0) return;

#pragma unroll
    for (int j = 0; j < 17; ++j) {
        ac0[j] += xs[rr * 19 + j];
        ac1[j] += xs[(rr + 64) * 19 + j];
    }

    WRITE_ROW(ac0, rowBase + rr);
    WRITE_ROW(ac1, rowBase + rr + 64);
}

extern "C" void kernel_launch(void* const* d_in, const int* in_sizes, int n_in,
                              void* d_out, int out_size, void* d_ws, size_t ws_size,
                              hipStream_t stream) {
    const float* x   = (const float*)d_in[0];
    const float* Wa  = (const float*)d_in[1];
    const float* ba  = (const float*)d_in[2];
    const float* Wb  = (const float*)d_in[3];
    const float* bb  = (const float*)d_in[4];
    const float* Wc1 = (const float*)d_in[5];
    const float* bc1 = (const float*)d_in[6];
    const float* Wc2 = (const float*)d_in[7];
    const float* bc2 = (const float*)d_in[8];
    const float* Wc3 = (const float*)d_in[9];
    const float* bc3 = (const float*)d_in[10];
    const float* Wc4 = (const float*)d_in[11];
    const float* bc4 = (const float*)d_in[12];

    const int B  = in_sizes[0] / HDIM;
    const int nb = (B + RPB - 1) / RPB;

    hipLaunchKernelGGL(hier_fused, dim3(nb), dim3(128), 0, stream,
                       x, Wa, ba, Wb, bb, Wc1, bc1, Wc2, bc2, Wc3, bc3, Wc4, bc4,
                       (float*)d_out, B);
}